// Round 1
// baseline (14388.579 us; speedup 1.0000x reference)
//
#include <hip/hip_runtime.h>
#include <math.h>

// ---------------- problem constants ----------------
constexpr int NN   = 50000;          // nodes
constexpr int NE   = 800000;         // edges (before self loops)
constexpr int ETOT = NE + NN;        // 850000 with self loops
constexpr int F_IN = 128;
constexpr int HID  = 64;
constexpr int HEADS = 4;
constexpr int HC1  = HEADS * HID;    // 256
constexpr int NG   = 64;             // graphs
constexpr float SLOPE = 0.2f;

// ---------------- helpers ----------------
__device__ __forceinline__ void atomAddF(float* p, float v) {
  __hip_atomic_fetch_add(p, v, __ATOMIC_RELAXED, __HIP_MEMORY_SCOPE_AGENT);
}
__device__ __forceinline__ float lrelu(float v) { return v >= 0.f ? v : SLOPE * v; }
// monotone float -> uint key (unsigned compare == float compare)
__device__ __forceinline__ unsigned fkey(float f) {
  unsigned b = __float_as_uint(f);
  return (b & 0x80000000u) ? ~b : (b | 0x80000000u);
}
__device__ __forceinline__ float fdec(unsigned u) {
  unsigned b = (u & 0x80000000u) ? (u ^ 0x80000000u) : ~u;
  return __uint_as_float(b);
}

// ---------------- GEMM1: h1 = x @ W1  [N,128]x[128,256], + attention scores ----------------
__global__ __launch_bounds__(256) void gemm1_kernel(
    const float* __restrict__ x, const float* __restrict__ W1,
    const float* __restrict__ asrc, const float* __restrict__ adst,
    float* __restrict__ h1, float* __restrict__ ssrc, float* __restrict__ sdst) {
  __shared__ float xs[8][F_IN];
  __shared__ float hs[8][HC1];
  const int n0 = blockIdx.x * 8;
  const int t  = threadIdx.x;            // 256 threads, t = output column
  for (int i = t; i < 8 * F_IN; i += 256)
    xs[i >> 7][i & 127] = x[(size_t)n0 * F_IN + i];
  __syncthreads();
  float acc[8] = {0.f,0.f,0.f,0.f,0.f,0.f,0.f,0.f};
  for (int k = 0; k < F_IN; ++k) {
    float w = W1[k * HC1 + t];
#pragma unroll
    for (int r = 0; r < 8; ++r) acc[r] += xs[r][k] * w;
  }
#pragma unroll
  for (int r = 0; r < 8; ++r) {
    h1[(size_t)(n0 + r) * HC1 + t] = acc[r];
    hs[r][t] = acc[r];
  }
  __syncthreads();
  if (t < 64) {                          // 8 rows x 4 heads x {src,dst}
    int r = t >> 3, h = (t >> 1) & 3, isdst = t & 1;
    const float* a = isdst ? adst : asrc;
    float s = 0.f;
    for (int c = 0; c < HID; ++c) s += hs[r][h * HID + c] * a[h * HID + c];
    (isdst ? sdst : ssrc)[(n0 + r) * HEADS + h] = s;
  }
}

// ---------------- GEMM2: h2 = o1 @ W2  [N,256]x[256,64], + attention scores ----------------
__global__ __launch_bounds__(64) void gemm2_kernel(
    const float* __restrict__ o1, const float* __restrict__ W2,
    const float* __restrict__ asrc, const float* __restrict__ adst,
    float* __restrict__ h2, float* __restrict__ ssrc, float* __restrict__ sdst) {
  __shared__ float xs[8][HC1];
  __shared__ float hs[8][HID];
  const int n0 = blockIdx.x * 8;
  const int t  = threadIdx.x;            // 64 threads, t = output column
  for (int i = t; i < 8 * HC1; i += 64)
    xs[i >> 8][i & 255] = o1[(size_t)n0 * HC1 + i];
  __syncthreads();
  float acc[8] = {0.f,0.f,0.f,0.f,0.f,0.f,0.f,0.f};
  for (int k = 0; k < HC1; ++k) {
    float w = W2[k * HID + t];
#pragma unroll
    for (int r = 0; r < 8; ++r) acc[r] += xs[r][k] * w;
  }
#pragma unroll
  for (int r = 0; r < 8; ++r) {
    h2[(size_t)(n0 + r) * HID + t] = acc[r];
    hs[r][t] = acc[r];
  }
  __syncthreads();
  if (t < 16) {                          // 8 rows x {src,dst}
    int r = t >> 1, isdst = t & 1;
    const float* a = isdst ? adst : asrc;
    float s = 0.f;
    for (int c = 0; c < HID; ++c) s += hs[r][c] * a[c];
    (isdst ? sdst : ssrc)[n0 + r] = s;
  }
}

// ---------------- edge pass A: segment max (as uint keys) ----------------
template<int H>
__global__ void edge_max_kernel(const int* __restrict__ esrc, const int* __restrict__ edst,
                                const float* __restrict__ ss, const float* __restrict__ sd,
                                unsigned* __restrict__ mk) {
  int idx = blockIdx.x * blockDim.x + threadIdx.x;
  if (idx >= ETOT * H) return;
  int e = idx / H, h = idx - e * H;
  int s = (e < NE) ? esrc[e] : (e - NE);
  int d = (e < NE) ? edst[e] : (e - NE);
  float v = lrelu(ss[s * H + h] + sd[d * H + h]);
  atomicMax(&mk[d * H + h], fkey(v));
}

// decode keys -> float max (zero-init key decodes to NaN -> 0, matches isfinite guard)
template<int H>
__global__ void decode_max_kernel(const unsigned* __restrict__ mk, float* __restrict__ m) {
  int i = blockIdx.x * blockDim.x + threadIdx.x;
  if (i >= NN * H) return;
  float v = fdec(mk[i]);
  m[i] = isfinite(v) ? v : 0.f;
}

// ---------------- edge pass B: softmax denominator ----------------
template<int H>
__global__ void edge_den_kernel(const int* __restrict__ esrc, const int* __restrict__ edst,
                                const float* __restrict__ ss, const float* __restrict__ sd,
                                const float* __restrict__ m, float* __restrict__ den) {
  int idx = blockIdx.x * blockDim.x + threadIdx.x;
  if (idx >= ETOT * H) return;
  int e = idx / H, h = idx - e * H;
  int s = (e < NE) ? esrc[e] : (e - NE);
  int d = (e < NE) ? edst[e] : (e - NE);
  float v = lrelu(ss[s * H + h] + sd[d * H + h]);
  atomAddF(&den[d * H + h], expf(v - m[d * H + h]));
}

// ---------------- edge pass C: alpha-weighted aggregation ----------------
template<int H>
__global__ void edge_agg_kernel(const int* __restrict__ esrc, const int* __restrict__ edst,
                                const float* __restrict__ ss, const float* __restrict__ sd,
                                const float* __restrict__ m, const float* __restrict__ den,
                                const float* __restrict__ hsrc, float* __restrict__ outd) {
  int idx = blockIdx.x * blockDim.x + threadIdx.x;
  if (idx >= ETOT * H) return;
  int e = idx / H, h = idx - e * H;
  int s = (e < NE) ? esrc[e] : (e - NE);
  int d = (e < NE) ? edst[e] : (e - NE);
  float v = lrelu(ss[s * H + h] + sd[d * H + h]);
  float alpha = expf(v - m[d * H + h]) / (den[d * H + h] + 1e-16f);
  const float4* hp = (const float4*)(hsrc + ((size_t)s * H + h) * HID);
  float* op = outd + ((size_t)d * H + h) * HID;
#pragma unroll
  for (int c = 0; c < HID / 4; ++c) {
    float4 hv = hp[c];
    atomAddF(op + 4 * c + 0, alpha * hv.x);
    atomAddF(op + 4 * c + 1, alpha * hv.y);
    atomAddF(op + 4 * c + 2, alpha * hv.z);
    atomAddF(op + 4 * c + 3, alpha * hv.w);
  }
}

// ---------------- bias + ELU (in place) ----------------
__global__ void bias_elu_kernel(float* __restrict__ v, const float* __restrict__ b,
                                int total, int cmask) {
  int i = blockIdx.x * blockDim.x + threadIdx.x;
  if (i >= total) return;
  float t = v[i] + b[i & cmask];
  v[i] = t > 0.f ? t : expm1f(t);
}

// ---------------- pooling ----------------
__global__ void pool_cnt_kernel(const int* __restrict__ batch, float* __restrict__ cnt) {
  int n = blockIdx.x * blockDim.x + threadIdx.x;
  if (n < NN) atomAddF(&cnt[batch[n]], 1.f);
}
__global__ void pool_sum_kernel(const float* __restrict__ o2, const int* __restrict__ batch,
                                float* __restrict__ sums) {
  int i = blockIdx.x * blockDim.x + threadIdx.x;
  if (i >= NN * HID) return;
  int n = i >> 6, c = i & 63;
  atomAddF(&sums[batch[n] * HID + c], o2[i]);
}

// ---------------- head: mean, FC, log_softmax ----------------
__global__ void head_kernel(const float* __restrict__ sums, const float* __restrict__ cnt,
                            const float* __restrict__ fcw, const float* __restrict__ fcb,
                            float* __restrict__ out) {
  int g = threadIdx.x;
  if (g >= NG) return;
  float c = fmaxf(cnt[g], 1.f);
  float l0 = fcb[0], l1 = fcb[1];
  for (int k = 0; k < HID; ++k) {
    float p = sums[g * HID + k] / c;
    l0 += p * fcw[k * 2 + 0];
    l1 += p * fcw[k * 2 + 1];
  }
  float mx = fmaxf(l0, l1);
  float lse = mx + logf(expf(l0 - mx) + expf(l1 - mx));
  out[g * 2 + 0] = l0 - lse;
  out[g * 2 + 1] = l1 - lse;
}

// ---------------- launch ----------------
extern "C" void kernel_launch(void* const* d_in, const int* in_sizes, int n_in,
                              void* d_out, int out_size, void* d_ws, size_t ws_size,
                              hipStream_t stream) {
  const float* x    = (const float*)d_in[0];
  const int*   ei   = (const int*)d_in[1];
  const int*   batch= (const int*)d_in[2];
  const float* W1   = (const float*)d_in[3];
  const float* as1  = (const float*)d_in[4];
  const float* ad1  = (const float*)d_in[5];
  const float* b1   = (const float*)d_in[6];
  const float* W2   = (const float*)d_in[7];
  const float* as2  = (const float*)d_in[8];
  const float* ad2  = (const float*)d_in[9];
  const float* b2   = (const float*)d_in[10];
  const float* fcw  = (const float*)d_in[11];
  const float* fcb  = (const float*)d_in[12];
  float* out = (float*)d_out;
  float* ws  = (float*)d_ws;

  const int* esrc = ei;
  const int* edst = ei + NE;

  // ---- workspace layout (floats) ----
  size_t off = 0;
  float* h1   = ws + off; off += (size_t)NN * HC1;     // also reused: h2 at base, o2 at +NN*HID
  float* o1   = ws + off; off += (size_t)NN * HC1;
  // zero-init block (contiguous): mk1, den1, mk2, den2, sums, cnt
  float* zbase = ws + off;
  unsigned* mk1 = (unsigned*)(ws + off); off += (size_t)NN * HEADS;
  float* den1 = ws + off; off += (size_t)NN * HEADS;
  unsigned* mk2 = (unsigned*)(ws + off); off += NN;
  float* den2 = ws + off; off += NN;
  float* sums = ws + off; off += NG * HID;
  float* cnt  = ws + off; off += NG;
  size_t zcount = (size_t)(ws + off - zbase);
  // non-init scratch
  float* ss1 = ws + off; off += (size_t)NN * HEADS;
  float* sd1 = ws + off; off += (size_t)NN * HEADS;
  float* m1  = ws + off; off += (size_t)NN * HEADS;
  float* ss2 = ws + off; off += NN;
  float* sd2 = ws + off; off += NN;
  float* m2  = ws + off; off += NN;
  // layer-2 reuse of h1 region
  float* h2 = h1;                      // [NN, 64]
  float* o2 = h1 + (size_t)NN * HID;   // [NN, 64] — memset AFTER layer-1 agg (aliases h1)

  // ---- zero inits (o2 deferred: aliases h1) ----
  hipMemsetAsync(o1, 0, (size_t)NN * HC1 * sizeof(float), stream);
  hipMemsetAsync(zbase, 0, zcount * sizeof(float), stream);

  // ---- layer 1 ----
  gemm1_kernel<<<NN / 8, 256, 0, stream>>>(x, W1, as1, ad1, h1, ss1, sd1);
  {
    int tot = ETOT * HEADS, blk = 256, grd = (tot + blk - 1) / blk;
    edge_max_kernel<HEADS><<<grd, blk, 0, stream>>>(esrc, edst, ss1, sd1, mk1);
    decode_max_kernel<HEADS><<<(NN * HEADS + 255) / 256, 256, 0, stream>>>(mk1, m1);
    edge_den_kernel<HEADS><<<grd, blk, 0, stream>>>(esrc, edst, ss1, sd1, m1, den1);
    edge_agg_kernel<HEADS><<<grd, blk, 0, stream>>>(esrc, edst, ss1, sd1, m1, den1, h1, o1);
  }
  bias_elu_kernel<<<(NN * HC1 + 255) / 256, 256, 0, stream>>>(o1, b1, NN * HC1, HC1 - 1);

  // ---- layer 2 (h1 now dead; reuse region) ----
  hipMemsetAsync(o2, 0, (size_t)NN * HID * sizeof(float), stream);
  gemm2_kernel<<<NN / 8, 64, 0, stream>>>(o1, W2, as2, ad2, h2, ss2, sd2);
  {
    int tot = ETOT, blk = 256, grd = (tot + blk - 1) / blk;
    edge_max_kernel<1><<<grd, blk, 0, stream>>>(esrc, edst, ss2, sd2, mk2);
    decode_max_kernel<1><<<(NN + 255) / 256, 256, 0, stream>>>(mk2, m2);
    edge_den_kernel<1><<<grd, blk, 0, stream>>>(esrc, edst, ss2, sd2, m2, den2);
    edge_agg_kernel<1><<<grd, blk, 0, stream>>>(esrc, edst, ss2, sd2, m2, den2, h2, o2);
  }
  bias_elu_kernel<<<(NN * HID + 255) / 256, 256, 0, stream>>>(o2, b2, NN * HID, HID - 1);

  // ---- pool + head ----
  pool_cnt_kernel<<<(NN + 255) / 256, 256, 0, stream>>>(batch, cnt);
  pool_sum_kernel<<<(NN * HID + 255) / 256, 256, 0, stream>>>(o2, batch, sums);
  head_kernel<<<1, 64, 0, stream>>>(sums, cnt, fcw, fcb, out);
}

// Round 2
// 685.662 us; speedup vs baseline: 20.9849x; 20.9849x over previous
//
#include <hip/hip_runtime.h>
#include <math.h>

// ---------------- problem constants ----------------
constexpr int NN   = 50000;          // nodes
constexpr int NE   = 800000;         // edges (before self loops)
constexpr int ETOT = NE + NN;        // 850000 with self loops
constexpr int F_IN = 128;
constexpr int HID  = 64;
constexpr int HEADS = 4;
constexpr int HC1  = HEADS * HID;    // 256
constexpr int NG   = 64;             // graphs
constexpr float SLOPE = 0.2f;

__device__ __forceinline__ float lrelu(float v) { return v >= 0.f ? v : SLOPE * v; }

// ================= CSR build =================
__global__ void deg_kernel(const int* __restrict__ edst, int* __restrict__ deg) {
  int e = blockIdx.x * blockDim.x + threadIdx.x;
  if (e >= ETOT) return;
  int d = (e < NE) ? edst[e] : (e - NE);
  atomicAdd(&deg[d], 1);
}

// single-block exclusive scan of deg[NN] -> rowptr[NN+1] (wave-shuffle based)
__global__ __launch_bounds__(1024) void scan_kernel(const int* __restrict__ deg,
                                                    int* __restrict__ rowptr) {
  __shared__ int wsum[16];
  const int t = threadIdx.x, lane = t & 63, w = t >> 6;
  int carry = 0;
  if (t == 0) rowptr[0] = 0;
  for (int base = 0; base < NN; base += 1024) {
    int i = base + t;
    int v = (i < NN) ? deg[i] : 0;
    int sv = v;
#pragma unroll
    for (int o = 1; o < 64; o <<= 1) {
      int u = __shfl_up(sv, o, 64);
      if (lane >= o) sv += u;
    }
    if (lane == 63) wsum[w] = sv;
    __syncthreads();
    if (w == 0 && lane < 16) {
      int ws = wsum[lane];
#pragma unroll
      for (int o = 1; o < 16; o <<= 1) {
        int u = __shfl_up(ws, o, 64);
        if (lane >= o) ws += u;
      }
      wsum[lane] = ws;
    }
    __syncthreads();
    int offset = carry + (w > 0 ? wsum[w - 1] : 0);
    if (i < NN) rowptr[i + 1] = sv + offset;
    carry += wsum[15];
    __syncthreads();   // protect wsum before next-iteration write
  }
}

__global__ void scatter_kernel(const int* __restrict__ esrc, const int* __restrict__ edst,
                               const int* __restrict__ rowptr, int* __restrict__ cursor,
                               int* __restrict__ ssorted) {
  int e = blockIdx.x * blockDim.x + threadIdx.x;
  if (e >= ETOT) return;
  int s = (e < NE) ? esrc[e] : (e - NE);
  int d = (e < NE) ? edst[e] : (e - NE);
  int slot = rowptr[d] + atomicAdd(&cursor[d], 1);
  ssorted[slot] = s;
}

// graph boundaries in sorted batch via binary search
__global__ void gstart_kernel(const int* __restrict__ batch, int* __restrict__ gstart) {
  int g = blockIdx.x * blockDim.x + threadIdx.x;
  if (g > NG) return;
  int lo = 0, hi = NN;
  while (lo < hi) { int mid = (lo + hi) >> 1; if (batch[mid] < g) lo = mid + 1; else hi = mid; }
  gstart[g] = lo;
}

// ================= GEMMs (+ fused attention scores) =================
__global__ __launch_bounds__(256) void gemm1_kernel(
    const float* __restrict__ x, const float* __restrict__ W1,
    const float* __restrict__ asrc, const float* __restrict__ adst,
    float* __restrict__ h1, float* __restrict__ ssrc, float* __restrict__ sdst) {
  __shared__ float xs[8][F_IN];
  __shared__ float hs[8][HC1];
  const int n0 = blockIdx.x * 8;
  const int t  = threadIdx.x;            // t = output column
  for (int i = t; i < 8 * F_IN; i += 256)
    xs[i >> 7][i & 127] = x[(size_t)n0 * F_IN + i];
  __syncthreads();
  float acc[8] = {0.f,0.f,0.f,0.f,0.f,0.f,0.f,0.f};
  for (int k = 0; k < F_IN; ++k) {
    float w = W1[k * HC1 + t];
#pragma unroll
    for (int r = 0; r < 8; ++r) acc[r] += xs[r][k] * w;
  }
#pragma unroll
  for (int r = 0; r < 8; ++r) {
    h1[(size_t)(n0 + r) * HC1 + t] = acc[r];
    hs[r][t] = acc[r];
  }
  __syncthreads();
  if (t < 64) {                          // 8 rows x 4 heads x {src,dst}
    int r = t >> 3, h = (t >> 1) & 3, isdst = t & 1;
    const float* a = isdst ? adst : asrc;
    float s = 0.f;
    for (int c = 0; c < HID; ++c) s += hs[r][h * HID + c] * a[h * HID + c];
    (isdst ? sdst : ssrc)[(n0 + r) * HEADS + h] = s;
  }
}

__global__ __launch_bounds__(64) void gemm2_kernel(
    const float* __restrict__ o1, const float* __restrict__ W2,
    const float* __restrict__ asrc, const float* __restrict__ adst,
    float* __restrict__ h2, float* __restrict__ ssrc, float* __restrict__ sdst) {
  __shared__ float xs[8][HC1];
  __shared__ float hs[8][HID];
  const int n0 = blockIdx.x * 8;
  const int t  = threadIdx.x;            // 64 threads, t = output column
  for (int i = t; i < 8 * HC1; i += 64)
    xs[i >> 8][i & 255] = o1[(size_t)n0 * HC1 + i];
  __syncthreads();
  float acc[8] = {0.f,0.f,0.f,0.f,0.f,0.f,0.f,0.f};
  for (int k = 0; k < HC1; ++k) {
    float w = W2[k * HID + t];
#pragma unroll
    for (int r = 0; r < 8; ++r) acc[r] += xs[r][k] * w;
  }
#pragma unroll
  for (int r = 0; r < 8; ++r) {
    h2[(size_t)(n0 + r) * HID + t] = acc[r];
    hs[r][t] = acc[r];
  }
  __syncthreads();
  if (t < 16) {
    int r = t >> 1, isdst = t & 1;
    const float* a = isdst ? adst : asrc;
    float s = 0.f;
    for (int c = 0; c < HID; ++c) s += hs[r][c] * a[c];
    (isdst ? sdst : ssrc)[n0 + r] = s;
  }
}

// ================= fused GAT gather (softmax + aggregate), one wave per (dst,head) =================
template<int H>
__global__ __launch_bounds__(256) void gat_gather_kernel(
    const int* __restrict__ rowptr, const int* __restrict__ ssorted,
    const float* __restrict__ ss, const float* __restrict__ sd,
    const float* __restrict__ h, float* __restrict__ outp) {
  const int wid  = (blockIdx.x * 256 + threadIdx.x) >> 6;   // global wave id
  const int lane = threadIdx.x & 63;
  if (wid >= NN * H) return;                                // wave-uniform
  const int d  = wid / H;
  const int hh = wid - d * H;
  const int start = rowptr[d], end = rowptr[d + 1];
  const float sdv = sd[d * H + hh];
  float acc = 0.f;

  if (end - start <= 64) {
    // fast path (deg<=64, ~always: mean degree 17): scores live in one register
    int e = start + lane;
    float v = -INFINITY;
    int s = 0;
    if (e < end) {
      s = ssorted[e];
      v = lrelu(ss[s * H + hh] + sdv);
    }
    float mx = v;
#pragma unroll
    for (int o = 1; o < 64; o <<= 1) mx = fmaxf(mx, __shfl_xor(mx, o, 64));
    float p = (e < end) ? __expf(v - mx) : 0.f;
    float den = p;
#pragma unroll
    for (int o = 1; o < 64; o <<= 1) den += __shfl_xor(den, o, 64);
    float inv = 1.f / (den + 1e-16f);
    int cnt = end - start;
    for (int j = 0; j < cnt; ++j) {
      float alpha = __shfl(p, j, 64) * inv;
      int sj = __shfl(s, j, 64);
      acc += alpha * h[((size_t)sj * H + hh) * HID + lane];
    }
  } else {
    // general path (rare high-degree rows)
    float mx = -INFINITY;
    for (int base = start; base < end; base += 64) {
      int e = base + lane;
      float v = (e < end) ? lrelu(ss[ssorted[e] * H + hh] + sdv) : -INFINITY;
#pragma unroll
      for (int o = 1; o < 64; o <<= 1) v = fmaxf(v, __shfl_xor(v, o, 64));
      mx = fmaxf(mx, v);
    }
    float den = 0.f;
    for (int base = start; base < end; base += 64) {
      int e = base + lane;
      float p = (e < end) ? __expf(lrelu(ss[ssorted[e] * H + hh] + sdv) - mx) : 0.f;
#pragma unroll
      for (int o = 1; o < 64; o <<= 1) p += __shfl_xor(p, o, 64);
      den += p;
    }
    float inv = 1.f / (den + 1e-16f);
    for (int base = start; base < end; base += 64) {
      int e = base + lane;
      int s = 0; float p = 0.f;
      if (e < end) { s = ssorted[e]; p = __expf(lrelu(ss[s * H + hh] + sdv) - mx); }
      int cnt = min(64, end - base);
      for (int j = 0; j < cnt; ++j) {
        float alpha = __shfl(p, j, 64) * inv;
        int sj = __shfl(s, j, 64);
        acc += alpha * h[((size_t)sj * H + hh) * HID + lane];
      }
    }
  }
  outp[((size_t)d * H + hh) * HID + lane] = acc;
}

// ---------------- bias + ELU (in place) ----------------
__global__ void bias_elu_kernel(float* __restrict__ v, const float* __restrict__ b,
                                int total, int cmask) {
  int i = blockIdx.x * blockDim.x + threadIdx.x;
  if (i >= total) return;
  float t = v[i] + b[i & cmask];
  v[i] = t > 0.f ? t : expm1f(t);
}

// ---------------- pooling: one block per graph over contiguous node range ----------------
__global__ __launch_bounds__(256) void pool_kernel(const float* __restrict__ o2,
                                                   const int* __restrict__ gstart,
                                                   float* __restrict__ pooled) {
  __shared__ float red[4][HID];
  int g = blockIdx.x;
  int t = threadIdx.x;
  int c = t & 63, r = t >> 6;          // 4 node-rows in flight
  int s0 = gstart[g], s1 = gstart[g + 1];
  float acc = 0.f;
  for (int n = s0 + r; n < s1; n += 4) acc += o2[(size_t)n * HID + c];
  red[r][c] = acc;
  __syncthreads();
  if (r == 0) {
    float v = red[0][c] + red[1][c] + red[2][c] + red[3][c];
    pooled[g * HID + c] = v / fmaxf((float)(s1 - s0), 1.f);
  }
}

// ---------------- head: FC + log_softmax ----------------
__global__ void head_kernel(const float* __restrict__ pooled,
                            const float* __restrict__ fcw, const float* __restrict__ fcb,
                            float* __restrict__ out) {
  int g = threadIdx.x;
  if (g >= NG) return;
  float l0 = fcb[0], l1 = fcb[1];
  for (int k = 0; k < HID; ++k) {
    float p = pooled[g * HID + k];
    l0 += p * fcw[k * 2 + 0];
    l1 += p * fcw[k * 2 + 1];
  }
  float mx = fmaxf(l0, l1);
  float lse = mx + logf(expf(l0 - mx) + expf(l1 - mx));
  out[g * 2 + 0] = l0 - lse;
  out[g * 2 + 1] = l1 - lse;
}

// ---------------- launch ----------------
extern "C" void kernel_launch(void* const* d_in, const int* in_sizes, int n_in,
                              void* d_out, int out_size, void* d_ws, size_t ws_size,
                              hipStream_t stream) {
  const float* x    = (const float*)d_in[0];
  const int*   ei   = (const int*)d_in[1];
  const int*   batch= (const int*)d_in[2];
  const float* W1   = (const float*)d_in[3];
  const float* as1  = (const float*)d_in[4];
  const float* ad1  = (const float*)d_in[5];
  const float* b1   = (const float*)d_in[6];
  const float* W2   = (const float*)d_in[7];
  const float* as2  = (const float*)d_in[8];
  const float* ad2  = (const float*)d_in[9];
  const float* b2   = (const float*)d_in[10];
  const float* fcw  = (const float*)d_in[11];
  const float* fcb  = (const float*)d_in[12];
  float* out = (float*)d_out;
  float* ws  = (float*)d_ws;

  const int* esrc = ei;
  const int* edst = ei + NE;

  // ---- workspace layout (floats) ----
  size_t off = 0;
  float* h1 = ws + off; off += (size_t)NN * HC1;   // layer2 reuses: h2 at base, o2 at +NN*HID
  float* o1 = ws + off; off += (size_t)NN * HC1;
  float* ss1 = ws + off; off += (size_t)NN * HEADS;
  float* sd1 = ws + off; off += (size_t)NN * HEADS;
  float* ss2 = ws + off; off += NN;
  float* sd2 = ws + off; off += NN;
  float* pooled = ws + off; off += NG * HID;
  int* rowptr  = (int*)(ws + off); off += NN + 1;
  int* ssorted = (int*)(ws + off); off += ETOT;
  int* gstart  = (int*)(ws + off); off += NG + 1;
  // zero-init block: deg + cursor (contiguous)
  int* deg    = (int*)(ws + off); off += NN;
  int* cursor = (int*)(ws + off); off += NN;
  float* h2 = h1;                       // [NN, 64]
  float* o2 = h1 + (size_t)NN * HID;    // [NN, 64]

  hipMemsetAsync(deg, 0, 2 * (size_t)NN * sizeof(int), stream);

  // ---- CSR build (shared by both layers) ----
  deg_kernel<<<(ETOT + 255) / 256, 256, 0, stream>>>(edst, deg);
  scan_kernel<<<1, 1024, 0, stream>>>(deg, rowptr);
  scatter_kernel<<<(ETOT + 255) / 256, 256, 0, stream>>>(esrc, edst, rowptr, cursor, ssorted);
  gstart_kernel<<<1, 128, 0, stream>>>(batch, gstart);

  // ---- layer 1 ----
  gemm1_kernel<<<NN / 8, 256, 0, stream>>>(x, W1, as1, ad1, h1, ss1, sd1);
  gat_gather_kernel<HEADS><<<NN * HEADS / 4, 256, 0, stream>>>(rowptr, ssorted, ss1, sd1, h1, o1);
  bias_elu_kernel<<<(NN * HC1 + 255) / 256, 256, 0, stream>>>(o1, b1, NN * HC1, HC1 - 1);

  // ---- layer 2 (reuses h1 region: h2 at base, o2 above it) ----
  gemm2_kernel<<<NN / 8, 64, 0, stream>>>(o1, W2, as2, ad2, h2, ss2, sd2);
  gat_gather_kernel<1><<<NN / 4, 256, 0, stream>>>(rowptr, ssorted, ss2, sd2, h2, o2);
  bias_elu_kernel<<<(NN * HID + 255) / 256, 256, 0, stream>>>(o2, b2, NN * HID, HID - 1);

  // ---- pool + head ----
  pool_kernel<<<NG, 256, 0, stream>>>(o2, gstart, pooled);
  head_kernel<<<1, 64, 0, stream>>>(pooled, fcw, fcb, out);
}

// Round 3
// 563.347 us; speedup vs baseline: 25.5412x; 1.2171x over previous
//
#include <hip/hip_runtime.h>
#include <math.h>

// ---------------- problem constants ----------------
constexpr int NN   = 50000;          // nodes
constexpr int NE   = 800000;         // edges (before self loops)
constexpr int ETOT = NE + NN;        // 850000 with self loops
constexpr int F_IN = 128;
constexpr int HID  = 64;
constexpr int HEADS = 4;
constexpr int HC1  = HEADS * HID;    // 256
constexpr int NG   = 64;             // graphs
constexpr float SLOPE = 0.2f;

__device__ __forceinline__ float lrelu(float v) { return v >= 0.f ? v : SLOPE * v; }
__device__ __forceinline__ float elu(float v) { return v > 0.f ? v : expm1f(v); }

// ================= CSR build =================
__global__ void deg_kernel(const int* __restrict__ edst, int* __restrict__ deg) {
  int e = blockIdx.x * blockDim.x + threadIdx.x;
  if (e >= ETOT) return;
  int d = (e < NE) ? edst[e] : (e - NE);
  atomicAdd(&deg[d], 1);
}

// single-block exclusive scan of deg[NN] -> rowptr[NN+1]
__global__ __launch_bounds__(1024) void scan_kernel(const int* __restrict__ deg,
                                                    int* __restrict__ rowptr) {
  __shared__ int wsum[16];
  const int t = threadIdx.x, lane = t & 63, w = t >> 6;
  int carry = 0;
  if (t == 0) rowptr[0] = 0;
  for (int base = 0; base < NN; base += 1024) {
    int i = base + t;
    int v = (i < NN) ? deg[i] : 0;
    int sv = v;
#pragma unroll
    for (int o = 1; o < 64; o <<= 1) {
      int u = __shfl_up(sv, o, 64);
      if (lane >= o) sv += u;
    }
    if (lane == 63) wsum[w] = sv;
    __syncthreads();
    if (w == 0 && lane < 16) {
      int ws = wsum[lane];
#pragma unroll
      for (int o = 1; o < 16; o <<= 1) {
        int u = __shfl_up(ws, o, 64);
        if (lane >= o) ws += u;
      }
      wsum[lane] = ws;
    }
    __syncthreads();
    int offset = carry + (w > 0 ? wsum[w - 1] : 0);
    if (i < NN) rowptr[i + 1] = sv + offset;
    carry += wsum[15];
    __syncthreads();
  }
}

__global__ void scatter_kernel(const int* __restrict__ esrc, const int* __restrict__ edst,
                               const int* __restrict__ rowptr, int* __restrict__ cursor,
                               int* __restrict__ ssorted) {
  int e = blockIdx.x * blockDim.x + threadIdx.x;
  if (e >= ETOT) return;
  int s = (e < NE) ? esrc[e] : (e - NE);
  int d = (e < NE) ? edst[e] : (e - NE);
  int slot = rowptr[d] + atomicAdd(&cursor[d], 1);
  ssorted[slot] = s;
}

__global__ void gstart_kernel(const int* __restrict__ batch, int* __restrict__ gstart) {
  int g = blockIdx.x * blockDim.x + threadIdx.x;
  if (g > NG) return;
  int lo = 0, hi = NN;
  while (lo < hi) { int mid = (lo + hi) >> 1; if (batch[mid] < g) lo = mid + 1; else hi = mid; }
  gstart[g] = lo;
}

// ================= GEMMs (+ fused attention scores) =================
__global__ __launch_bounds__(256) void gemm1_kernel(
    const float* __restrict__ x, const float* __restrict__ W1,
    const float* __restrict__ asrc, const float* __restrict__ adst,
    float* __restrict__ h1, float* __restrict__ ssrc, float* __restrict__ sdst) {
  __shared__ float xs[8][F_IN];
  __shared__ float hs[8][HC1];
  const int n0 = blockIdx.x * 8;
  const int t  = threadIdx.x;
  for (int i = t; i < 8 * F_IN; i += 256)
    xs[i >> 7][i & 127] = x[(size_t)n0 * F_IN + i];
  __syncthreads();
  float acc[8] = {0.f,0.f,0.f,0.f,0.f,0.f,0.f,0.f};
  for (int k = 0; k < F_IN; ++k) {
    float w = W1[k * HC1 + t];
#pragma unroll
    for (int r = 0; r < 8; ++r) acc[r] += xs[r][k] * w;
  }
#pragma unroll
  for (int r = 0; r < 8; ++r) {
    h1[(size_t)(n0 + r) * HC1 + t] = acc[r];
    hs[r][t] = acc[r];
  }
  __syncthreads();
  if (t < 64) {
    int r = t >> 3, h = (t >> 1) & 3, isdst = t & 1;
    const float* a = isdst ? adst : asrc;
    float s = 0.f;
    for (int c = 0; c < HID; ++c) s += hs[r][h * HID + c] * a[h * HID + c];
    (isdst ? sdst : ssrc)[(n0 + r) * HEADS + h] = s;
  }
}

__global__ __launch_bounds__(64) void gemm2_kernel(
    const float* __restrict__ o1, const float* __restrict__ W2,
    const float* __restrict__ asrc, const float* __restrict__ adst,
    float* __restrict__ h2, float* __restrict__ ssrc, float* __restrict__ sdst) {
  __shared__ float xs[8][HC1];
  __shared__ float hs[8][HID];
  const int n0 = blockIdx.x * 8;
  const int t  = threadIdx.x;
  for (int i = t; i < 8 * HC1; i += 64)
    xs[i >> 8][i & 255] = o1[(size_t)n0 * HC1 + i];
  __syncthreads();
  float acc[8] = {0.f,0.f,0.f,0.f,0.f,0.f,0.f,0.f};
  for (int k = 0; k < HC1; ++k) {
    float w = W2[k * HID + t];
#pragma unroll
    for (int r = 0; r < 8; ++r) acc[r] += xs[r][k] * w;
  }
#pragma unroll
  for (int r = 0; r < 8; ++r) {
    h2[(size_t)(n0 + r) * HID + t] = acc[r];
    hs[r][t] = acc[r];
  }
  __syncthreads();
  if (t < 16) {
    int r = t >> 1, isdst = t & 1;
    const float* a = isdst ? adst : asrc;
    float s = 0.f;
    for (int c = 0; c < HID; ++c) s += hs[r][c] * a[c];
    (isdst ? sdst : ssrc)[n0 + r] = s;
  }
}

// ================= fused GAT gather, layer 1 (H=4): one wave per dst =================
// Score phase: lane = j*4+h handles (edge j, head h), 16 edges/pass, 2 regs -> deg<=32 fast.
// Agg phase:   lane L owns channels 4L..4L+3 (head L>>4); one float4 load per edge per lane.
__global__ __launch_bounds__(256) void gat_gather4_kernel(
    const int* __restrict__ rowptr, const int* __restrict__ ssorted,
    const float* __restrict__ ss, const float* __restrict__ sd,
    const float* __restrict__ h, const float* __restrict__ bias,
    float* __restrict__ outp) {
  const int d    = (blockIdx.x * 256 + threadIdx.x) >> 6;
  const int lane = threadIdx.x & 63;
  if (d >= NN) return;
  const int start = rowptr[d];
  const int deg   = rowptr[d + 1] - start;
  const int hsel  = lane & 3;     // score-phase head
  const int hh    = lane >> 4;    // agg-phase head
  const float sdv = sd[d * 4 + hsel];
  float4 acc = make_float4(0.f, 0.f, 0.f, 0.f);

  if (deg <= 32) {
    const int j0 = lane >> 2;
    int s0 = 0, s1 = 0;
    float v0 = -INFINITY, v1 = -INFINITY;
    if (j0 < deg)      { s0 = ssorted[start + j0];      v0 = lrelu(ss[s0 * 4 + hsel] + sdv); }
    if (j0 + 16 < deg) { s1 = ssorted[start + j0 + 16]; v1 = lrelu(ss[s1 * 4 + hsel] + sdv); }
    float mx = fmaxf(v0, v1);
#pragma unroll
    for (int o = 4; o < 64; o <<= 1) mx = fmaxf(mx, __shfl_xor(mx, o, 64));
    float p0 = (j0 < deg)      ? __expf(v0 - mx) : 0.f;
    float p1 = (j0 + 16 < deg) ? __expf(v1 - mx) : 0.f;
    float den = p0 + p1;
#pragma unroll
    for (int o = 4; o < 64; o <<= 1) den += __shfl_xor(den, o, 64);
    const float inv = 1.f / (den + 1e-16f);
    const float pa0 = p0 * inv, pa1 = p1 * inv;
    const int c1 = min(deg, 16);
    for (int j = 0; j < c1; ++j) {
      float alpha = __shfl(pa0, j * 4 + hh, 64);
      int   sj    = __shfl(s0, j * 4, 64);
      float4 hv = *(const float4*)(h + (size_t)sj * HC1 + lane * 4);
      acc.x += alpha * hv.x; acc.y += alpha * hv.y;
      acc.z += alpha * hv.z; acc.w += alpha * hv.w;
    }
    for (int j = 16; j < deg; ++j) {
      float alpha = __shfl(pa1, (j - 16) * 4 + hh, 64);
      int   sj    = __shfl(s1, (j - 16) * 4, 64);
      float4 hv = *(const float4*)(h + (size_t)sj * HC1 + lane * 4);
      acc.x += alpha * hv.x; acc.y += alpha * hv.y;
      acc.z += alpha * hv.z; acc.w += alpha * hv.w;
    }
  } else {
    // chunked two-pass (rare: P(deg>32) ~ 1e-4)
    float mx = -INFINITY;
    for (int base = 0; base < deg; base += 16) {
      int j = base + (lane >> 2);
      float v = (j < deg) ? lrelu(ss[ssorted[start + j] * 4 + hsel] + sdv) : -INFINITY;
#pragma unroll
      for (int o = 4; o < 64; o <<= 1) v = fmaxf(v, __shfl_xor(v, o, 64));
      mx = fmaxf(mx, v);
    }
    float den = 0.f;
    for (int base = 0; base < deg; base += 16) {
      int j = base + (lane >> 2);
      float p = (j < deg) ? __expf(lrelu(ss[ssorted[start + j] * 4 + hsel] + sdv) - mx) : 0.f;
#pragma unroll
      for (int o = 4; o < 64; o <<= 1) p += __shfl_xor(p, o, 64);
      den += p;
    }
    const float inv = 1.f / (den + 1e-16f);
    for (int base = 0; base < deg; base += 16) {
      int j = base + (lane >> 2);
      int s = 0; float pa = 0.f;
      if (j < deg) {
        s = ssorted[start + j];
        pa = __expf(lrelu(ss[s * 4 + hsel] + sdv) - mx) * inv;
      }
      int cnt = min(16, deg - base);
      for (int jj = 0; jj < cnt; ++jj) {
        float alpha = __shfl(pa, jj * 4 + hh, 64);
        int   sj    = __shfl(s, jj * 4, 64);
        float4 hv = *(const float4*)(h + (size_t)sj * HC1 + lane * 4);
        acc.x += alpha * hv.x; acc.y += alpha * hv.y;
        acc.z += alpha * hv.z; acc.w += alpha * hv.w;
      }
    }
  }
  const float4 bv = *(const float4*)(bias + lane * 4);
  float4 r;
  r.x = elu(acc.x + bv.x); r.y = elu(acc.y + bv.y);
  r.z = elu(acc.z + bv.z); r.w = elu(acc.w + bv.w);
  *(float4*)(outp + (size_t)d * HC1 + lane * 4) = r;
}

// ================= fused GAT gather, layer 2 (H=1): one wave per dst =================
// Score: lane j handles edge j (deg<=64 fast path). Agg: 4 edges in flight,
// lane group eg=lane>>4 takes edge j+eg, 16 lanes x float4 cover the 64-ch row.
__global__ __launch_bounds__(256) void gat_gather1_kernel(
    const int* __restrict__ rowptr, const int* __restrict__ ssorted,
    const float* __restrict__ ss, const float* __restrict__ sd,
    const float* __restrict__ h, const float* __restrict__ bias,
    float* __restrict__ outp) {
  const int d    = (blockIdx.x * 256 + threadIdx.x) >> 6;
  const int lane = threadIdx.x & 63;
  if (d >= NN) return;
  const int start = rowptr[d];
  const int deg   = rowptr[d + 1] - start;
  const int eg = lane >> 4;       // edge subgroup
  const int cq = lane & 15;       // channel quad
  const float sdv = sd[d];
  float4 acc = make_float4(0.f, 0.f, 0.f, 0.f);

  if (deg <= 64) {
    int s = 0; float v = -INFINITY;
    if (lane < deg) { s = ssorted[start + lane]; v = lrelu(ss[s] + sdv); }
    float mx = v;
#pragma unroll
    for (int o = 1; o < 64; o <<= 1) mx = fmaxf(mx, __shfl_xor(mx, o, 64));
    float p = (lane < deg) ? __expf(v - mx) : 0.f;
    float den = p;
#pragma unroll
    for (int o = 1; o < 64; o <<= 1) den += __shfl_xor(den, o, 64);
    const float pa = p / (den + 1e-16f);
    for (int j = 0; j < deg; j += 4) {
      int jj = j + eg;
      float alpha = (jj < deg) ? __shfl(pa, jj, 64) : 0.f;
      int   sj    = __shfl(s, jj < 63 ? jj : 63, 64);
      float4 hv = *(const float4*)(h + (size_t)sj * HID + cq * 4);
      acc.x += alpha * hv.x; acc.y += alpha * hv.y;
      acc.z += alpha * hv.z; acc.w += alpha * hv.w;
    }
  } else {
    // chunked two-pass (essentially never taken)
    float mx = -INFINITY;
    for (int base = 0; base < deg; base += 64) {
      int j = base + lane;
      float v = (j < deg) ? lrelu(ss[ssorted[start + j]] + sdv) : -INFINITY;
#pragma unroll
      for (int o = 1; o < 64; o <<= 1) v = fmaxf(v, __shfl_xor(v, o, 64));
      mx = fmaxf(mx, v);
    }
    float den = 0.f;
    for (int base = 0; base < deg; base += 64) {
      int j = base + lane;
      float p = (j < deg) ? __expf(lrelu(ss[ssorted[start + j]] + sdv) - mx) : 0.f;
#pragma unroll
      for (int o = 1; o < 64; o <<= 1) p += __shfl_xor(p, o, 64);
      den += p;
    }
    const float inv = 1.f / (den + 1e-16f);
    for (int base = 0; base < deg; base += 64) {
      int j = base + lane;
      int s = 0; float pa = 0.f;
      if (j < deg) { s = ssorted[start + j]; pa = __expf(lrelu(ss[s] + sdv) - mx) * inv; }
      int cnt = min(64, deg - base);
      for (int j2 = 0; j2 < cnt; j2 += 4) {
        int jj = j2 + eg;
        float alpha = (jj < cnt) ? __shfl(pa, jj, 64) : 0.f;
        int   sj    = __shfl(s, jj < 63 ? jj : 63, 64);
        float4 hv = *(const float4*)(h + (size_t)sj * HID + cq * 4);
        acc.x += alpha * hv.x; acc.y += alpha * hv.y;
        acc.z += alpha * hv.z; acc.w += alpha * hv.w;
      }
    }
  }
  // sum partials across the 4 edge subgroups
#pragma unroll
  for (int o = 16; o < 64; o <<= 1) {
    acc.x += __shfl_xor(acc.x, o, 64);
    acc.y += __shfl_xor(acc.y, o, 64);
    acc.z += __shfl_xor(acc.z, o, 64);
    acc.w += __shfl_xor(acc.w, o, 64);
  }
  if (eg == 0) {
    const float4 bv = *(const float4*)(bias + cq * 4);
    float4 r;
    r.x = elu(acc.x + bv.x); r.y = elu(acc.y + bv.y);
    r.z = elu(acc.z + bv.z); r.w = elu(acc.w + bv.w);
    *(float4*)(outp + (size_t)d * HID + cq * 4) = r;
  }
}

// ---------------- pooling: one block per graph ----------------
__global__ __launch_bounds__(256) void pool_kernel(const float* __restrict__ o2,
                                                   const int* __restrict__ gstart,
                                                   float* __restrict__ pooled) {
  __shared__ float red[4][HID];
  int g = blockIdx.x;
  int t = threadIdx.x;
  int c = t & 63, r = t >> 6;
  int s0 = gstart[g], s1 = gstart[g + 1];
  float acc = 0.f;
  for (int n = s0 + r; n < s1; n += 4) acc += o2[(size_t)n * HID + c];
  red[r][c] = acc;
  __syncthreads();
  if (r == 0) {
    float v = red[0][c] + red[1][c] + red[2][c] + red[3][c];
    pooled[g * HID + c] = v / fmaxf((float)(s1 - s0), 1.f);
  }
}

// ---------------- head: FC + log_softmax ----------------
__global__ void head_kernel(const float* __restrict__ pooled,
                            const float* __restrict__ fcw, const float* __restrict__ fcb,
                            float* __restrict__ out) {
  int g = threadIdx.x;
  if (g >= NG) return;
  float l0 = fcb[0], l1 = fcb[1];
  for (int k = 0; k < HID; ++k) {
    float p = pooled[g * HID + k];
    l0 += p * fcw[k * 2 + 0];
    l1 += p * fcw[k * 2 + 1];
  }
  float mx = fmaxf(l0, l1);
  float lse = mx + logf(expf(l0 - mx) + expf(l1 - mx));
  out[g * 2 + 0] = l0 - lse;
  out[g * 2 + 1] = l1 - lse;
}

// ---------------- launch ----------------
extern "C" void kernel_launch(void* const* d_in, const int* in_sizes, int n_in,
                              void* d_out, int out_size, void* d_ws, size_t ws_size,
                              hipStream_t stream) {
  const float* x    = (const float*)d_in[0];
  const int*   ei   = (const int*)d_in[1];
  const int*   batch= (const int*)d_in[2];
  const float* W1   = (const float*)d_in[3];
  const float* as1  = (const float*)d_in[4];
  const float* ad1  = (const float*)d_in[5];
  const float* b1   = (const float*)d_in[6];
  const float* W2   = (const float*)d_in[7];
  const float* as2  = (const float*)d_in[8];
  const float* ad2  = (const float*)d_in[9];
  const float* b2   = (const float*)d_in[10];
  const float* fcw  = (const float*)d_in[11];
  const float* fcb  = (const float*)d_in[12];
  float* out = (float*)d_out;
  float* ws  = (float*)d_ws;

  const int* esrc = ei;
  const int* edst = ei + NE;

  // ---- workspace layout (floats) ----
  size_t off = 0;
  float* h1 = ws + off; off += (size_t)NN * HC1;   // layer2 reuses: h2 at base, o2 at +NN*HID
  float* o1 = ws + off; off += (size_t)NN * HC1;
  float* ss1 = ws + off; off += (size_t)NN * HEADS;
  float* sd1 = ws + off; off += (size_t)NN * HEADS;
  float* ss2 = ws + off; off += NN;
  float* sd2 = ws + off; off += NN;
  float* pooled = ws + off; off += NG * HID;
  int* rowptr  = (int*)(ws + off); off += NN + 1;
  int* ssorted = (int*)(ws + off); off += ETOT;
  int* gstart  = (int*)(ws + off); off += NG + 1;
  int* deg    = (int*)(ws + off); off += NN;       // zero-init
  int* cursor = (int*)(ws + off); off += NN;       // zero-init
  float* h2 = h1;                       // [NN, 64]
  float* o2 = h1 + (size_t)NN * HID;    // [NN, 64]

  hipMemsetAsync(deg, 0, 2 * (size_t)NN * sizeof(int), stream);

  // ---- CSR build (shared by both layers) ----
  deg_kernel<<<(ETOT + 255) / 256, 256, 0, stream>>>(edst, deg);
  scan_kernel<<<1, 1024, 0, stream>>>(deg, rowptr);
  scatter_kernel<<<(ETOT + 255) / 256, 256, 0, stream>>>(esrc, edst, rowptr, cursor, ssorted);
  gstart_kernel<<<1, 128, 0, stream>>>(batch, gstart);

  // ---- layer 1 ----
  gemm1_kernel<<<NN / 8, 256, 0, stream>>>(x, W1, as1, ad1, h1, ss1, sd1);
  gat_gather4_kernel<<<(NN + 3) / 4, 256, 0, stream>>>(rowptr, ssorted, ss1, sd1, h1, b1, o1);

  // ---- layer 2 (reuses h1 region: h2 at base, o2 above it) ----
  gemm2_kernel<<<NN / 8, 64, 0, stream>>>(o1, W2, as2, ad2, h2, ss2, sd2);
  gat_gather1_kernel<<<(NN + 3) / 4, 256, 0, stream>>>(rowptr, ssorted, ss2, sd2, h2, b2, o2);

  // ---- pool + head ----
  pool_kernel<<<NG, 256, 0, stream>>>(o2, gstart, pooled);
  head_kernel<<<1, 64, 0, stream>>>(pooled, fcw, fcb, out);
}

// Round 4
// 515.188 us; speedup vs baseline: 27.9288x; 1.0935x over previous
//
#include <hip/hip_runtime.h>
#include <hip/hip_fp16.h>
#include <math.h>

// ---------------- problem constants ----------------
constexpr int NN   = 50000;          // nodes
constexpr int NE   = 800000;         // edges (before self loops)
constexpr int ETOT = NE + NN;        // 850000 with self loops
constexpr int F_IN = 128;
constexpr int HID  = 64;
constexpr int HEADS = 4;
constexpr int HC1  = HEADS * HID;    // 256
constexpr int NG   = 64;             // graphs
constexpr float SLOPE = 0.2f;

__device__ __forceinline__ float lrelu(float v) { return v >= 0.f ? v : SLOPE * v; }
__device__ __forceinline__ float elu(float v) { return v > 0.f ? v : expm1f(v); }

// ================= CSR build =================
__global__ void deg_kernel(const int* __restrict__ edst, int* __restrict__ deg) {
  int e = blockIdx.x * blockDim.x + threadIdx.x;
  if (e >= ETOT) return;
  int d = (e < NE) ? edst[e] : (e - NE);
  atomicAdd(&deg[d], 1);
}

// single-block exclusive scan of deg[NN] -> rowptr[NN+1]
__global__ __launch_bounds__(1024) void scan_kernel(const int* __restrict__ deg,
                                                    int* __restrict__ rowptr) {
  __shared__ int wsum[16];
  const int t = threadIdx.x, lane = t & 63, w = t >> 6;
  int carry = 0;
  if (t == 0) rowptr[0] = 0;
  for (int base = 0; base < NN; base += 1024) {
    int i = base + t;
    int v = (i < NN) ? deg[i] : 0;
    int sv = v;
#pragma unroll
    for (int o = 1; o < 64; o <<= 1) {
      int u = __shfl_up(sv, o, 64);
      if (lane >= o) sv += u;
    }
    if (lane == 63) wsum[w] = sv;
    __syncthreads();
    if (w == 0 && lane < 16) {
      int ws = wsum[lane];
#pragma unroll
      for (int o = 1; o < 16; o <<= 1) {
        int u = __shfl_up(ws, o, 64);
        if (lane >= o) ws += u;
      }
      wsum[lane] = ws;
    }
    __syncthreads();
    int offset = carry + (w > 0 ? wsum[w - 1] : 0);
    if (i < NN) rowptr[i + 1] = sv + offset;
    carry += wsum[15];
    __syncthreads();
  }
}

__global__ void scatter_kernel(const int* __restrict__ esrc, const int* __restrict__ edst,
                               const int* __restrict__ rowptr, int* __restrict__ cursor,
                               int* __restrict__ ssorted) {
  int e = blockIdx.x * blockDim.x + threadIdx.x;
  if (e >= ETOT) return;
  int s = (e < NE) ? esrc[e] : (e - NE);
  int d = (e < NE) ? edst[e] : (e - NE);
  int slot = rowptr[d] + atomicAdd(&cursor[d], 1);
  ssorted[slot] = s;
}

__global__ void gstart_kernel(const int* __restrict__ batch, int* __restrict__ gstart) {
  int g = blockIdx.x * blockDim.x + threadIdx.x;
  if (g > NG) return;
  int lo = 0, hi = NN;
  while (lo < hi) { int mid = (lo + hi) >> 1; if (batch[mid] < g) lo = mid + 1; else hi = mid; }
  gstart[g] = lo;
}

// ================= GEMMs (+ fused attention scores; h written fp16) =================
__global__ __launch_bounds__(256) void gemm1_kernel(
    const float* __restrict__ x, const float* __restrict__ W1,
    const float* __restrict__ asrc, const float* __restrict__ adst,
    __half* __restrict__ h1, float* __restrict__ ssrc, float* __restrict__ sdst) {
  __shared__ float xs[8][F_IN];
  __shared__ float hs[8][HC1 + 1];      // +1 pad: score phase banks
  const int n0 = blockIdx.x * 8;
  const int t  = threadIdx.x;
  // stage 8x128 floats = 256 float4, one per thread
  ((float4*)&xs[0][0])[t] = ((const float4*)(x + (size_t)n0 * F_IN))[t];
  __syncthreads();
  float acc[8] = {0.f,0.f,0.f,0.f,0.f,0.f,0.f,0.f};
  for (int k = 0; k < F_IN; ++k) {
    float w = W1[k * HC1 + t];
#pragma unroll
    for (int r = 0; r < 8; ++r) acc[r] += xs[r][k] * w;
  }
#pragma unroll
  for (int r = 0; r < 8; ++r) {
    h1[(size_t)(n0 + r) * HC1 + t] = __float2half(acc[r]);
    hs[r][t] = acc[r];
  }
  __syncthreads();
  if (t < 64) {                          // 8 rows x 4 heads x {src,dst}
    int r = t >> 3, h = (t >> 1) & 3, isdst = t & 1;
    const float* a = isdst ? adst : asrc;
    float s = 0.f;
    for (int c = 0; c < HID; ++c) s += hs[r][h * HID + c] * a[h * HID + c];
    (isdst ? sdst : ssrc)[(n0 + r) * HEADS + h] = s;
  }
}

__global__ __launch_bounds__(64) void gemm2_kernel(
    const float* __restrict__ o1, const float* __restrict__ W2,
    const float* __restrict__ asrc, const float* __restrict__ adst,
    __half* __restrict__ h2, float* __restrict__ ssrc, float* __restrict__ sdst) {
  __shared__ float xs[8][HC1];
  __shared__ float hs[8][HID + 1];      // +1 pad
  const int n0 = blockIdx.x * 8;
  const int t  = threadIdx.x;
  // stage 8x256 floats = 512 float4, 64 threads -> 8 iters
  {
    const float4* src = (const float4*)(o1 + (size_t)n0 * HC1);
    float4* dst = (float4*)&xs[0][0];
    for (int i = t; i < 8 * HC1 / 4; i += 64) dst[i] = src[i];
  }
  __syncthreads();
  float acc[8] = {0.f,0.f,0.f,0.f,0.f,0.f,0.f,0.f};
  for (int k = 0; k < HC1; ++k) {
    float w = W2[k * HID + t];
#pragma unroll
    for (int r = 0; r < 8; ++r) acc[r] += xs[r][k] * w;
  }
#pragma unroll
  for (int r = 0; r < 8; ++r) {
    h2[(size_t)(n0 + r) * HID + t] = __float2half(acc[r]);
    hs[r][t] = acc[r];
  }
  __syncthreads();
  if (t < 16) {
    int r = t >> 1, isdst = t & 1;
    const float* a = isdst ? adst : asrc;
    float s = 0.f;
    for (int c = 0; c < HID; ++c) s += hs[r][c] * a[c];
    (isdst ? sdst : ssrc)[n0 + r] = s;
  }
}

// ================= fused GAT gather, layer 1 (H=4): one wave per dst =================
// Score phase: lane = j*4+h handles (edge j, head h), 16 edges/pass.
// Agg phase:   lane L owns channels 4L..4L+3 (head L>>4); one uint2 (4 fp16) per edge.
__global__ __launch_bounds__(256) void gat_gather4_kernel(
    const int* __restrict__ rowptr, const int* __restrict__ ssorted,
    const float* __restrict__ ss, const float* __restrict__ sd,
    const __half* __restrict__ h, const float* __restrict__ bias,
    float* __restrict__ outp) {
  const int d    = (blockIdx.x * 256 + threadIdx.x) >> 6;
  const int lane = threadIdx.x & 63;
  if (d >= NN) return;
  const int start = rowptr[d];
  const int deg   = rowptr[d + 1] - start;
  const int hsel  = lane & 3;     // score-phase head
  const int hh    = lane >> 4;    // agg-phase head
  const float sdv = sd[d * 4 + hsel];
  float4 acc = make_float4(0.f, 0.f, 0.f, 0.f);

  if (deg <= 32) {
    const int j0 = lane >> 2;
    int s0 = 0, s1 = 0;
    float v0 = -INFINITY, v1 = -INFINITY;
    if (j0 < deg)      { s0 = ssorted[start + j0];      v0 = lrelu(ss[s0 * 4 + hsel] + sdv); }
    if (j0 + 16 < deg) { s1 = ssorted[start + j0 + 16]; v1 = lrelu(ss[s1 * 4 + hsel] + sdv); }
    float mx = fmaxf(v0, v1);
#pragma unroll
    for (int o = 4; o < 64; o <<= 1) mx = fmaxf(mx, __shfl_xor(mx, o, 64));
    float p0 = (j0 < deg)      ? __expf(v0 - mx) : 0.f;
    float p1 = (j0 + 16 < deg) ? __expf(v1 - mx) : 0.f;
    float den = p0 + p1;
#pragma unroll
    for (int o = 4; o < 64; o <<= 1) den += __shfl_xor(den, o, 64);
    const float inv = 1.f / (den + 1e-16f);
    const float pa0 = p0 * inv, pa1 = p1 * inv;
    const int c1 = min(deg, 16);
    for (int j = 0; j < c1; ++j) {
      float alpha = __shfl(pa0, j * 4 + hh, 64);
      int   sj    = __shfl(s0, j * 4, 64);
      uint2 u = *(const uint2*)(h + (size_t)sj * HC1 + lane * 4);
      float2 f0 = __half22float2(*(const __half2*)&u.x);
      float2 f1 = __half22float2(*(const __half2*)&u.y);
      acc.x += alpha * f0.x; acc.y += alpha * f0.y;
      acc.z += alpha * f1.x; acc.w += alpha * f1.y;
    }
    for (int j = 16; j < deg; ++j) {
      float alpha = __shfl(pa1, (j - 16) * 4 + hh, 64);
      int   sj    = __shfl(s1, (j - 16) * 4, 64);
      uint2 u = *(const uint2*)(h + (size_t)sj * HC1 + lane * 4);
      float2 f0 = __half22float2(*(const __half2*)&u.x);
      float2 f1 = __half22float2(*(const __half2*)&u.y);
      acc.x += alpha * f0.x; acc.y += alpha * f0.y;
      acc.z += alpha * f1.x; acc.w += alpha * f1.y;
    }
  } else {
    // chunked two-pass (rare)
    float mx = -INFINITY;
    for (int base = 0; base < deg; base += 16) {
      int j = base + (lane >> 2);
      float v = (j < deg) ? lrelu(ss[ssorted[start + j] * 4 + hsel] + sdv) : -INFINITY;
#pragma unroll
      for (int o = 4; o < 64; o <<= 1) v = fmaxf(v, __shfl_xor(v, o, 64));
      mx = fmaxf(mx, v);
    }
    float den = 0.f;
    for (int base = 0; base < deg; base += 16) {
      int j = base + (lane >> 2);
      float p = (j < deg) ? __expf(lrelu(ss[ssorted[start + j] * 4 + hsel] + sdv) - mx) : 0.f;
#pragma unroll
      for (int o = 4; o < 64; o <<= 1) p += __shfl_xor(p, o, 64);
      den += p;
    }
    const float inv = 1.f / (den + 1e-16f);
    for (int base = 0; base < deg; base += 16) {
      int j = base + (lane >> 2);
      int s = 0; float pa = 0.f;
      if (j < deg) {
        s = ssorted[start + j];
        pa = __expf(lrelu(ss[s * 4 + hsel] + sdv) - mx) * inv;
      }
      int cnt = min(16, deg - base);
      for (int jj = 0; jj < cnt; ++jj) {
        float alpha = __shfl(pa, jj * 4 + hh, 64);
        int   sj    = __shfl(s, jj * 4, 64);
        uint2 u = *(const uint2*)(h + (size_t)sj * HC1 + lane * 4);
        float2 f0 = __half22float2(*(const __half2*)&u.x);
        float2 f1 = __half22float2(*(const __half2*)&u.y);
        acc.x += alpha * f0.x; acc.y += alpha * f0.y;
        acc.z += alpha * f1.x; acc.w += alpha * f1.y;
      }
    }
  }
  const float4 bv = *(const float4*)(bias + lane * 4);
  float4 r;
  r.x = elu(acc.x + bv.x); r.y = elu(acc.y + bv.y);
  r.z = elu(acc.z + bv.z); r.w = elu(acc.w + bv.w);
  *(float4*)(outp + (size_t)d * HC1 + lane * 4) = r;
}

// ================= fused GAT gather, layer 2 (H=1): one wave per dst =================
__global__ __launch_bounds__(256) void gat_gather1_kernel(
    const int* __restrict__ rowptr, const int* __restrict__ ssorted,
    const float* __restrict__ ss, const float* __restrict__ sd,
    const __half* __restrict__ h, const float* __restrict__ bias,
    float* __restrict__ outp) {
  const int d    = (blockIdx.x * 256 + threadIdx.x) >> 6;
  const int lane = threadIdx.x & 63;
  if (d >= NN) return;
  const int start = rowptr[d];
  const int deg   = rowptr[d + 1] - start;
  const int eg = lane >> 4;       // edge subgroup
  const int cq = lane & 15;       // channel quad
  const float sdv = sd[d];
  float4 acc = make_float4(0.f, 0.f, 0.f, 0.f);

  if (deg <= 64) {
    int s = 0; float v = -INFINITY;
    if (lane < deg) { s = ssorted[start + lane]; v = lrelu(ss[s] + sdv); }
    float mx = v;
#pragma unroll
    for (int o = 1; o < 64; o <<= 1) mx = fmaxf(mx, __shfl_xor(mx, o, 64));
    float p = (lane < deg) ? __expf(v - mx) : 0.f;
    float den = p;
#pragma unroll
    for (int o = 1; o < 64; o <<= 1) den += __shfl_xor(den, o, 64);
    const float pa = p / (den + 1e-16f);
    for (int j = 0; j < deg; j += 4) {
      int jj = j + eg;
      float alpha = (jj < deg) ? __shfl(pa, jj, 64) : 0.f;
      int   sj    = __shfl(s, jj < 63 ? jj : 63, 64);
      uint2 u = *(const uint2*)(h + (size_t)sj * HID + cq * 4);
      float2 f0 = __half22float2(*(const __half2*)&u.x);
      float2 f1 = __half22float2(*(const __half2*)&u.y);
      acc.x += alpha * f0.x; acc.y += alpha * f0.y;
      acc.z += alpha * f1.x; acc.w += alpha * f1.y;
    }
  } else {
    // chunked two-pass (essentially never taken)
    float mx = -INFINITY;
    for (int base = 0; base < deg; base += 64) {
      int j = base + lane;
      float v = (j < deg) ? lrelu(ss[ssorted[start + j]] + sdv) : -INFINITY;
#pragma unroll
      for (int o = 1; o < 64; o <<= 1) v = fmaxf(v, __shfl_xor(v, o, 64));
      mx = fmaxf(mx, v);
    }
    float den = 0.f;
    for (int base = 0; base < deg; base += 64) {
      int j = base + lane;
      float p = (j < deg) ? __expf(lrelu(ss[ssorted[start + j]] + sdv) - mx) : 0.f;
#pragma unroll
      for (int o = 1; o < 64; o <<= 1) p += __shfl_xor(p, o, 64);
      den += p;
    }
    const float inv = 1.f / (den + 1e-16f);
    for (int base = 0; base < deg; base += 64) {
      int j = base + lane;
      int s = 0; float pa = 0.f;
      if (j < deg) { s = ssorted[start + j]; pa = __expf(lrelu(ss[s] + sdv) - mx) * inv; }
      int cnt = min(64, deg - base);
      for (int j2 = 0; j2 < cnt; j2 += 4) {
        int jj = j2 + eg;
        float alpha = (jj < cnt) ? __shfl(pa, jj, 64) : 0.f;
        int   sj    = __shfl(s, jj < 63 ? jj : 63, 64);
        uint2 u = *(const uint2*)(h + (size_t)sj * HID + cq * 4);
        float2 f0 = __half22float2(*(const __half2*)&u.x);
        float2 f1 = __half22float2(*(const __half2*)&u.y);
        acc.x += alpha * f0.x; acc.y += alpha * f0.y;
        acc.z += alpha * f1.x; acc.w += alpha * f1.y;
      }
    }
  }
#pragma unroll
  for (int o = 16; o < 64; o <<= 1) {
    acc.x += __shfl_xor(acc.x, o, 64);
    acc.y += __shfl_xor(acc.y, o, 64);
    acc.z += __shfl_xor(acc.z, o, 64);
    acc.w += __shfl_xor(acc.w, o, 64);
  }
  if (eg == 0) {
    const float4 bv = *(const float4*)(bias + cq * 4);
    float4 r;
    r.x = elu(acc.x + bv.x); r.y = elu(acc.y + bv.y);
    r.z = elu(acc.z + bv.z); r.w = elu(acc.w + bv.w);
    *(float4*)(outp + (size_t)d * HID + cq * 4) = r;
  }
}

// ---------------- pooling: one block per graph ----------------
__global__ __launch_bounds__(256) void pool_kernel(const float* __restrict__ o2,
                                                   const int* __restrict__ gstart,
                                                   float* __restrict__ pooled) {
  __shared__ float red[4][HID];
  int g = blockIdx.x;
  int t = threadIdx.x;
  int c = t & 63, r = t >> 6;
  int s0 = gstart[g], s1 = gstart[g + 1];
  float acc = 0.f;
  for (int n = s0 + r; n < s1; n += 4) acc += o2[(size_t)n * HID + c];
  red[r][c] = acc;
  __syncthreads();
  if (r == 0) {
    float v = red[0][c] + red[1][c] + red[2][c] + red[3][c];
    pooled[g * HID + c] = v / fmaxf((float)(s1 - s0), 1.f);
  }
}

// ---------------- head: FC + log_softmax ----------------
__global__ void head_kernel(const float* __restrict__ pooled,
                            const float* __restrict__ fcw, const float* __restrict__ fcb,
                            float* __restrict__ out) {
  int g = threadIdx.x;
  if (g >= NG) return;
  float l0 = fcb[0], l1 = fcb[1];
  for (int k = 0; k < HID; ++k) {
    float p = pooled[g * HID + k];
    l0 += p * fcw[k * 2 + 0];
    l1 += p * fcw[k * 2 + 1];
  }
  float mx = fmaxf(l0, l1);
  float lse = mx + logf(expf(l0 - mx) + expf(l1 - mx));
  out[g * 2 + 0] = l0 - lse;
  out[g * 2 + 1] = l1 - lse;
}

// ---------------- launch ----------------
extern "C" void kernel_launch(void* const* d_in, const int* in_sizes, int n_in,
                              void* d_out, int out_size, void* d_ws, size_t ws_size,
                              hipStream_t stream) {
  const float* x    = (const float*)d_in[0];
  const int*   ei   = (const int*)d_in[1];
  const int*   batch= (const int*)d_in[2];
  const float* W1   = (const float*)d_in[3];
  const float* as1  = (const float*)d_in[4];
  const float* ad1  = (const float*)d_in[5];
  const float* b1   = (const float*)d_in[6];
  const float* W2   = (const float*)d_in[7];
  const float* as2  = (const float*)d_in[8];
  const float* ad2  = (const float*)d_in[9];
  const float* b2   = (const float*)d_in[10];
  const float* fcw  = (const float*)d_in[11];
  const float* fcb  = (const float*)d_in[12];
  float* out = (float*)d_out;
  float* ws  = (float*)d_ws;

  const int* esrc = ei;
  const int* edst = ei + NE;

  // ---- workspace layout (float units) ----
  size_t off = 0;
  // fp16 region: h1 [NN,256] halves = NN*HC1/2 floats; layer 2 reuses it:
  //   h2 (fp16 [NN,64] = NN*HID/2 floats) at base, o2 (fp32 [NN,64]) right after.
  float* hreg = ws + off; off += (size_t)NN * HC1 / 2;
  float* o1   = ws + off; off += (size_t)NN * HC1;
  float* ss1 = ws + off; off += (size_t)NN * HEADS;
  float* sd1 = ws + off; off += (size_t)NN * HEADS;
  float* ss2 = ws + off; off += NN;
  float* sd2 = ws + off; off += NN;
  float* pooled = ws + off; off += NG * HID;
  int* rowptr  = (int*)(ws + off); off += NN + 1;
  int* ssorted = (int*)(ws + off); off += ETOT;
  int* gstart  = (int*)(ws + off); off += NG + 1;
  int* deg    = (int*)(ws + off); off += NN;       // zero-init
  int* cursor = (int*)(ws + off); off += NN;       // zero-init
  __half* h1 = (__half*)hreg;                          // [NN, 256] fp16
  __half* h2 = (__half*)hreg;                          // [NN, 64] fp16 (h1 dead by then)
  float*  o2 = hreg + (size_t)NN * HID / 2;            // [NN, 64] fp32

  hipMemsetAsync(deg, 0, 2 * (size_t)NN * sizeof(int), stream);

  // ---- CSR build (shared by both layers) ----
  deg_kernel<<<(ETOT + 255) / 256, 256, 0, stream>>>(edst, deg);
  scan_kernel<<<1, 1024, 0, stream>>>(deg, rowptr);
  scatter_kernel<<<(ETOT + 255) / 256, 256, 0, stream>>>(esrc, edst, rowptr, cursor, ssorted);
  gstart_kernel<<<1, 128, 0, stream>>>(batch, gstart);

  // ---- layer 1 ----
  gemm1_kernel<<<NN / 8, 256, 0, stream>>>(x, W1, as1, ad1, h1, ss1, sd1);
  gat_gather4_kernel<<<(NN + 3) / 4, 256, 0, stream>>>(rowptr, ssorted, ss1, sd1, h1, b1, o1);

  // ---- layer 2 ----
  gemm2_kernel<<<NN / 8, 64, 0, stream>>>(o1, W2, as2, ad2, h2, ss2, sd2);
  gat_gather1_kernel<<<(NN + 3) / 4, 256, 0, stream>>>(rowptr, ssorted, ss2, sd2, h2, b2, o2);

  // ---- pool + head ----
  pool_kernel<<<NG, 256, 0, stream>>>(o2, gstart, pooled);
  head_kernel<<<1, 64, 0, stream>>>(pooled, fcw, fcb, out);
}